// Round 6
// baseline (149.468 us; speedup 1.0000x reference)
//
#include <hip/hip_runtime.h>
#include <hip/hip_bf16.h>
#include <cstdint>

// Problem constants (features: [512, 16, 512] fp32 -> N=8192 rows, D=512)
#define N_TOT 8192
#define DDIM  512
#define DBYTES 512                     // bytes per row in fp8
#define NBLK  64                       // 8192 / 128 tile blocks per dim
#define NTRI  (NBLK * (NBLK + 1) / 2)  // 2080 lower-triangle blocks
constexpr float INV_T = 1.0f / 0.07f;

typedef uint8_t u8;
typedef __attribute__((ext_vector_type(8))) int i32x8_t;
typedef __attribute__((ext_vector_type(4))) float f32x4_t;

// ---- helpers ---------------------------------------------------------------

// VALU-pipe cross-lane add via DPP row_shr (16-lane row): sum lands in lane 15
// of each 16-lane group. dpp_ctrl must be a compile-time constant.
template <int CTRL>
__device__ __forceinline__ float dpp_shr_add(float v) {
  int sh = __builtin_amdgcn_update_dpp(0, __builtin_bit_cast(int, v),
                                       CTRL, 0xF, 0xF, true);
  return v + __builtin_bit_cast(float, sh);
}
#define DPP_ROW_SHR1 0x111
#define DPP_ROW_SHR2 0x112
#define DPP_ROW_SHR4 0x114
#define DPP_ROW_SHR8 0x118

// ---- kernel 1: row-normalize fp32 -> fp8 e4m3 (+ zero tsum and out) --------
// one wave per row; hw cvt_pk_fp8 (RNE, OCP e4m3 on gfx950). |x|<=1 so no sat.
__global__ __launch_bounds__(256) void normalize_kernel(const float* __restrict__ X,
                                                        u8* __restrict__ Xn,
                                                        float* __restrict__ tsum,
                                                        float* __restrict__ out) {
  if (blockIdx.x < 32) tsum[blockIdx.x * 256 + threadIdx.x] = 0.0f;
  if (blockIdx.x == 32 && threadIdx.x == 0) out[0] = 0.0f;
  const int lane = threadIdx.x & 63;
  const int row  = blockIdx.x * 4 + (threadIdx.x >> 6);
  const float4* xr = (const float4*)(X + (size_t)row * DDIM);
  float4 v0 = xr[lane];       // elements 4*lane .. +3
  float4 v1 = xr[lane + 64];  // elements 256+4*lane .. +3
  float s = v0.x * v0.x + v0.y * v0.y + v0.z * v0.z + v0.w * v0.w
          + v1.x * v1.x + v1.y * v1.y + v1.z * v1.z + v1.w * v1.w;
#pragma unroll
  for (int m = 1; m < 64; m <<= 1) s += __shfl_xor(s, m);
  const float scale = 1.0f / fmaxf(sqrtf(s), 1e-8f);
  int w0 = __builtin_amdgcn_cvt_pk_fp8_f32(v0.x * scale, v0.y * scale, 0, 0);
  w0     = __builtin_amdgcn_cvt_pk_fp8_f32(v0.z * scale, v0.w * scale, w0, 1);
  int w1 = __builtin_amdgcn_cvt_pk_fp8_f32(v1.x * scale, v1.y * scale, 0, 0);
  w1     = __builtin_amdgcn_cvt_pk_fp8_f32(v1.z * scale, v1.w * scale, w1, 1);
  uint32_t* orow = (uint32_t*)(Xn + (size_t)row * DBYTES);
  orow[lane]      = (uint32_t)w0;   // bytes 4*lane .. +3
  orow[lane + 64] = (uint32_t)w1;   // bytes 256+4*lane .. +3
}

// ---- kernel 2: lower-triangle tiles of C = Xn*Xn^T, fused exp row/col sums -
//
// R6: NO LDS, NO BARRIERS. Xn is 4 MB -- it fits in each XCD's 4 MB L2
// (and trivially in 256 MB L3). Staging it through LDS was pure overhead
// (measured: 2-phase=56us, dbuf=60, deep-vmcnt=94, 8-phase=74 -- all
// barrier/drain-bound; cf. guide common-mistake #7 / m169: drop staging
// when data L2-fits). MFMA fragments are loaded DIRECTLY from global:
// fragment lane (l15,quad) reads row (base+..+l15), bytes kc*128+quad*32
// (+16) -- 2x global_load_dwordx4 per fragment, same line footprint as the
// old coalesced staging. Waves are fully independent: compiler pipelines
// loads across the unrolled K-loop; ~3 blocks/CU of pure TLP hides L2
// latency. A/B bytes read 2x from L2 (wave redundancy) -- ~530 MB total,
// under the 34.5 TB/s L2 ceiling, partially absorbed by L1 line sharing.
//
// 128x128 tile, 256 threads = 4 waves in 2x2; each wave owns 64x64 via 4x4
// frags of mfma_scale 16x16x128 f8f6f4 (cbsz=blgp=0 -> e4m3, unit E8M0
// scales 0x7F).
__global__ __launch_bounds__(256, 2) void gemm_exp_rowsum(const u8* __restrict__ Xn,
                                                          float* __restrict__ tsum) {
  // triangular decode: blockIdx.x -> (bi >= bj)
  const int k = blockIdx.x;
  int bi = (int)((sqrtf(8.0f * (float)k + 1.0f) - 1.0f) * 0.5f);
  while ((bi + 1) * (bi + 2) / 2 <= k) ++bi;
  while (bi * (bi + 1) / 2 > k) --bi;
  const int bj = k - bi * (bi + 1) / 2;
  const int rowBase = bi * 128;
  const int colBase = bj * 128;
  const bool isDiag = (bi == bj);

  const int t    = threadIdx.x;   // 0..255
  const int lane = t & 63;
  const int l15  = lane & 15;
  const int quad = lane >> 4;
  const int w    = t >> 6;        // 0..3
  const int wm   = w >> 1;        // 0..1: row offset wm*64
  const int wn   = w & 1;         // 0..1: col offset wn*64

  f32x4_t acc[4][4];
#pragma unroll
  for (int i = 0; i < 4; i++)
#pragma unroll
    for (int j = 0; j < 4; j++) acc[i][j] = {0.f, 0.f, 0.f, 0.f};

  // 32-bit byte offsets into Xn (4 MB buffer): fragment (mi, kc) for this
  // lane = Xn[aoff[mi] + kc*128 .. +31]
  uint32_t aoff[4], boff[4];
#pragma unroll
  for (int mi = 0; mi < 4; mi++)
    aoff[mi] = (uint32_t)(rowBase + wm * 64 + mi * 16 + l15) * DBYTES + quad * 32;
#pragma unroll
  for (int ni = 0; ni < 4; ni++)
    boff[ni] = (uint32_t)(colBase + wn * 64 + ni * 16 + l15) * DBYTES + quad * 32;

#pragma unroll
  for (int kc = 0; kc < 4; kc++) {  // K-chunks of 128 bytes
    const int kb = kc * 128;
    i32x8_t a[4], b[4];
#pragma unroll
    for (int mi = 0; mi < 4; mi++) {
      int4 lo = *(const int4*)(Xn + aoff[mi] + kb);
      int4 hi = *(const int4*)(Xn + aoff[mi] + kb + 16);
      a[mi] = (i32x8_t){lo.x, lo.y, lo.z, lo.w, hi.x, hi.y, hi.z, hi.w};
    }
#pragma unroll
    for (int ni = 0; ni < 4; ni++) {
      int4 lo = *(const int4*)(Xn + boff[ni] + kb);
      int4 hi = *(const int4*)(Xn + boff[ni] + kb + 16);
      b[ni] = (i32x8_t){lo.x, lo.y, lo.z, lo.w, hi.x, hi.y, hi.z, hi.w};
    }
#pragma unroll
    for (int mi = 0; mi < 4; mi++)
#pragma unroll
      for (int ni = 0; ni < 4; ni++)
        acc[mi][ni] = __builtin_amdgcn_mfma_scale_f32_16x16x128_f8f6f4(
            a[mi], b[ni], acc[mi][ni], 0, 0, 0, 0x7F7F7F7Fu, 0, 0x7F7F7F7Fu);
  }

  // epilogue: e = exp((c-1)/T). C/D layout: col = lane&15, row = quad*4 + reg
  // (shape-determined, dtype-independent -- m121..m128).
  // Row-sum reduce over l15 on the VALU pipe (DPP row_shr; sum in lane 15).
  // Col-sums: 8 shuffles/wave on the quad axis.
  if (isDiag) {
#pragma unroll
    for (int mi = 0; mi < 4; mi++) {
#pragma unroll
      for (int r = 0; r < 4; r++) {
        const int row = rowBase + wm * 64 + mi * 16 + quad * 4 + r;
        float rs = 0.0f;
#pragma unroll
        for (int ni = 0; ni < 4; ni++) {
          const int col = colBase + wn * 64 + ni * 16 + l15;
          const float e = __expf((acc[mi][ni][r] - 1.0f) * INV_T);
          rs += (row == col) ? 0.0f : e;
        }
        rs = dpp_shr_add<DPP_ROW_SHR1>(rs);
        rs = dpp_shr_add<DPP_ROW_SHR2>(rs);
        rs = dpp_shr_add<DPP_ROW_SHR4>(rs);
        rs = dpp_shr_add<DPP_ROW_SHR8>(rs);
        if (l15 == 15) atomicAdd(&tsum[row], rs);
      }
    }
  } else {
    float csum[4] = {0.f, 0.f, 0.f, 0.f};
#pragma unroll
    for (int mi = 0; mi < 4; mi++) {
#pragma unroll
      for (int r = 0; r < 4; r++) {
        const int row = rowBase + wm * 64 + mi * 16 + quad * 4 + r;
        float rs = 0.0f;
#pragma unroll
        for (int ni = 0; ni < 4; ni++) {
          const float e = __expf((acc[mi][ni][r] - 1.0f) * INV_T);
          rs += e;
          csum[ni] += e;
        }
        rs = dpp_shr_add<DPP_ROW_SHR1>(rs);
        rs = dpp_shr_add<DPP_ROW_SHR2>(rs);
        rs = dpp_shr_add<DPP_ROW_SHR4>(rs);
        rs = dpp_shr_add<DPP_ROW_SHR8>(rs);
        if (l15 == 15) atomicAdd(&tsum[row], rs);
      }
    }
#pragma unroll
    for (int ni = 0; ni < 4; ni++) {
      csum[ni] += __shfl_xor(csum[ni], 16);
      csum[ni] += __shfl_xor(csum[ni], 32);
      if (quad == 0) atomicAdd(&tsum[colBase + wn * 64 + ni * 16 + l15], csum[ni]);
    }
  }
}

// ---- kernel 3: loss = mean_i log1p(t_i), 32 blocks + atomic accumulate -----
__global__ __launch_bounds__(256) void finalize_kernel(const float* __restrict__ tsum,
                                                       float* __restrict__ out) {
  const int i = blockIdx.x * 256 + threadIdx.x;
  float s = log1pf(tsum[i]);
#pragma unroll
  for (int m = 1; m < 64; m <<= 1) s += __shfl_xor(s, m);
  __shared__ float ws[4];
  if ((threadIdx.x & 63) == 0) ws[threadIdx.x >> 6] = s;
  __syncthreads();
  if (threadIdx.x == 0)
    atomicAdd(out, (ws[0] + ws[1] + ws[2] + ws[3]) * (1.0f / N_TOT));
}

// ---- launcher --------------------------------------------------------------
extern "C" void kernel_launch(void* const* d_in, const int* in_sizes, int n_in,
                              void* d_out, int out_size, void* d_ws, size_t ws_size,
                              hipStream_t stream) {
  const float* X = (const float*)d_in[0];
  float* out = (float*)d_out;

  float* tsum = (float*)d_ws;                       // 8192 fp32 = 32 KB
  u8* Xn = (u8*)d_ws + 65536;                       // 8192x512 fp8 = 4 MB

  normalize_kernel<<<N_TOT / 4, 256, 0, stream>>>(X, Xn, tsum, out);
  gemm_exp_rowsum<<<NTRI, 256, 0, stream>>>(Xn, tsum);
  finalize_kernel<<<N_TOT / 256, 256, 0, stream>>>(tsum, out);
}

// Round 7
// 116.863 us; speedup vs baseline: 1.2790x; 1.2790x over previous
//
#include <hip/hip_runtime.h>
#include <hip/hip_bf16.h>
#include <cstdint>

// Problem constants (features: [512, 16, 512] fp32 -> N=8192 rows, D=512)
#define N_TOT 8192
#define DDIM  512
#define DBYTES 512                     // bytes per row in fp8
#define NBLK  64                       // 8192 / 128 tile blocks per dim
#define NTRI  (NBLK * (NBLK + 1) / 2)  // 2080 lower-triangle blocks
#define GRIDB 512                      // persistent blocks (2 per CU)
constexpr float INV_T = 1.0f / 0.07f;

typedef uint8_t u8;
typedef __attribute__((ext_vector_type(8))) int i32x8_t;
typedef __attribute__((ext_vector_type(4))) float f32x4_t;

// ---- helpers ---------------------------------------------------------------

// async 16B global->LDS (global_load_lds_dwordx4). LDS dst is wave-uniform
// base + lane*16 (lane-contiguous) -- swizzle is applied to the GLOBAL src.
__device__ __forceinline__ void load16_to_lds(const void* g, void* l) {
  __builtin_amdgcn_global_load_lds(
      (const __attribute__((address_space(1))) unsigned int*)g,
      (__attribute__((address_space(3))) unsigned int*)l, 16, 0, 0);
}

#define WAIT_VMCNT(n)                                   \
  do {                                                  \
    asm volatile("s_waitcnt vmcnt(" #n ")" ::: "memory"); \
  } while (0)

// VALU-pipe cross-lane add via DPP row_shr (16-lane row): sum lands in lane 15
// of each 16-lane group. dpp_ctrl must be a compile-time constant.
template <int CTRL>
__device__ __forceinline__ float dpp_shr_add(float v) {
  int sh = __builtin_amdgcn_update_dpp(0, __builtin_bit_cast(int, v),
                                       CTRL, 0xF, 0xF, true);
  return v + __builtin_bit_cast(float, sh);
}
#define DPP_ROW_SHR1 0x111
#define DPP_ROW_SHR2 0x112
#define DPP_ROW_SHR4 0x114
#define DPP_ROW_SHR8 0x118

// triangular decode: tile index -> block-row bi (bi >= bj)
__device__ __forceinline__ int tri_decode_bi(int k) {
  int bi = (int)((sqrtf(8.0f * (float)k + 1.0f) - 1.0f) * 0.5f);
  while ((bi + 1) * (bi + 2) / 2 <= k) ++bi;
  while (bi * (bi + 1) / 2 > k) --bi;
  return bi;
}

// ---- kernel 1: row-normalize fp32 -> fp8 e4m3 (+ zero tsum and out) --------
// one wave per row; hw cvt_pk_fp8 (RNE, OCP e4m3 on gfx950). |x|<=1 so no sat.
__global__ __launch_bounds__(256) void normalize_kernel(const float* __restrict__ X,
                                                        u8* __restrict__ Xn,
                                                        float* __restrict__ tsum,
                                                        float* __restrict__ out) {
  if (blockIdx.x < 32) tsum[blockIdx.x * 256 + threadIdx.x] = 0.0f;
  if (blockIdx.x == 32 && threadIdx.x == 0) out[0] = 0.0f;
  const int lane = threadIdx.x & 63;
  const int row  = blockIdx.x * 4 + (threadIdx.x >> 6);
  const float4* xr = (const float4*)(X + (size_t)row * DDIM);
  float4 v0 = xr[lane];       // elements 4*lane .. +3
  float4 v1 = xr[lane + 64];  // elements 256+4*lane .. +3
  float s = v0.x * v0.x + v0.y * v0.y + v0.z * v0.z + v0.w * v0.w
          + v1.x * v1.x + v1.y * v1.y + v1.z * v1.z + v1.w * v1.w;
#pragma unroll
  for (int m = 1; m < 64; m <<= 1) s += __shfl_xor(s, m);
  const float scale = 1.0f / fmaxf(sqrtf(s), 1e-8f);
  int w0 = __builtin_amdgcn_cvt_pk_fp8_f32(v0.x * scale, v0.y * scale, 0, 0);
  w0     = __builtin_amdgcn_cvt_pk_fp8_f32(v0.z * scale, v0.w * scale, w0, 1);
  int w1 = __builtin_amdgcn_cvt_pk_fp8_f32(v1.x * scale, v1.y * scale, 0, 0);
  w1     = __builtin_amdgcn_cvt_pk_fp8_f32(v1.z * scale, v1.w * scale, w1, 1);
  uint32_t* orow = (uint32_t*)(Xn + (size_t)row * DBYTES);
  orow[lane]      = (uint32_t)w0;   // bytes 4*lane .. +3
  orow[lane + 64] = (uint32_t)w1;   // bytes 256+4*lane .. +3
}

// ---- kernel 2: lower-triangle tiles of C = Xn*Xn^T, fused exp row/col sums -
//
// R7: PERSISTENT BLOCKS + CONTINUOUS COUNTED-VMCNT PIPELINE. The 2-phase
// per-tile kernel (56us) pays pipeline fill/drain once per 4-chunk tile
// (2080 times). Here 512 persistent blocks (2/CU, 2 waves/SIMD) each walk
// ~4 tiles = ~16 contiguous K-chunks with ONE pipeline: at each chunk-step,
// issue the NEXT chunk's 8 global_load_lds into the other 32KB buffer, then
// s_waitcnt vmcnt(8) (counted -- in-flight chunk never drains) + raw
// s_barrier, then ds_read frags + 16 MFMA. At tile boundaries the next
// tile's chunk-0 latency hides under the exp/reduce/atomic epilogue.
// Fragment layout, XOR swizzle, epilogue identical to the verified R0/R5.
//
// 128x128 tile, 256 threads = 4 waves in 2x2; each wave owns 64x64 via 4x4
// frags of mfma_scale 16x16x128 f8f6f4 (cbsz=blgp=0 -> e4m3, unit E8M0
// scales 0x7F). LDS = 2 x (16KB A + 16KB B) = 64 KB -> 2 blocks/CU.
__global__ __launch_bounds__(256, 2) void gemm_exp_rowsum(const u8* __restrict__ Xn,
                                                          float* __restrict__ tsum) {
  __shared__ __align__(16) u8 sA[2][128 * 128];  // 2 x 16 KB
  __shared__ __align__(16) u8 sB[2][128 * 128];  // 2 x 16 KB

  const int tid  = threadIdx.x;   // 0..255
  const int lane = tid & 63;
  const int l15  = lane & 15;
  const int quad = lane >> 4;
  const int w    = tid >> 6;      // 0..3
  const int wm   = w >> 1;        // 0..1: row offset wm*64
  const int wn   = w & 1;         // 0..1: col offset wn*64

  // staging geometry: per panel-chunk 1024 granules of 16B (128 rows x 8);
  // thread handles granules tid, +256, +512, +768 -> rows srow,+32,+64,+96,
  // same goff ((srow+32)&7 == srow&7). XOR swizzle: granule (row,j) at slot
  // row*8 + (j^(row&7)); staging inverts the swizzle on the global source.
  const int srow = tid >> 3;
  const int goff = ((tid & 7) ^ (srow & 7)) * 16;

  int tt = blockIdx.x;                 // current tile index
  int bi = tri_decode_bi(tt);
  int bj = tt - bi * (bi + 1) / 2;
  const u8* gA = Xn + (size_t)(bi * 128 + srow) * DBYTES + goff;
  const u8* gB = Xn + (size_t)(bj * 128 + srow) * DBYTES + goff;

#define ISSUE(PA, PB, KB, BUF)                                                \
  do {                                                                        \
    _Pragma("unroll") for (int r = 0; r < 4; ++r) {                           \
      load16_to_lds((PA) + (size_t)(r * 32) * DBYTES + (KB),                  \
                    sA[BUF] + tid * 16 + r * 4096);                           \
      load16_to_lds((PB) + (size_t)(r * 32) * DBYTES + (KB),                  \
                    sB[BUF] + tid * 16 + r * 4096);                           \
    }                                                                         \
  } while (0)

#define COMPUTE(BUF)                                                          \
  do {                                                                        \
    i32x8_t a[4], b[4];                                                       \
    _Pragma("unroll") for (int mi = 0; mi < 4; mi++) {                        \
      const int row = wm * 64 + mi * 16 + l15;                                \
      const int s0 = ((quad * 2) ^ (row & 7)) * 16;                           \
      const int s1 = ((quad * 2 + 1) ^ (row & 7)) * 16;                       \
      int4 lo = *(const int4*)&sA[BUF][row * 128 + s0];                       \
      int4 hi = *(const int4*)&sA[BUF][row * 128 + s1];                       \
      a[mi] = (i32x8_t){lo.x, lo.y, lo.z, lo.w, hi.x, hi.y, hi.z, hi.w};      \
    }                                                                         \
    _Pragma("unroll") for (int ni = 0; ni < 4; ni++) {                        \
      const int row = wn * 64 + ni * 16 + l15;                                \
      const int s0 = ((quad * 2) ^ (row & 7)) * 16;                           \
      const int s1 = ((quad * 2 + 1) ^ (row & 7)) * 16;                       \
      int4 lo = *(const int4*)&sB[BUF][row * 128 + s0];                       \
      int4 hi = *(const int4*)&sB[BUF][row * 128 + s1];                       \
      b[ni] = (i32x8_t){lo.x, lo.y, lo.z, lo.w, hi.x, hi.y, hi.z, hi.w};      \
    }                                                                         \
    __builtin_amdgcn_s_setprio(1);                                            \
    _Pragma("unroll") for (int mi = 0; mi < 4; mi++)                          \
        _Pragma("unroll") for (int ni = 0; ni < 4; ni++)                      \
            acc[mi][ni] = __builtin_amdgcn_mfma_scale_f32_16x16x128_f8f6f4(   \
                a[mi], b[ni], acc[mi][ni], 0, 0, 0, 0x7F7F7F7Fu, 0,           \
                0x7F7F7F7Fu);                                                 \
    __builtin_amdgcn_s_setprio(0);                                            \
  } while (0)

  // prologue: chunk 0 of first tile -> buf 0
  ISSUE(gA, gB, 0, 0);

  f32x4_t acc[4][4];
#pragma unroll
  for (int i = 0; i < 4; i++)
#pragma unroll
    for (int j = 0; j < 4; j++) acc[i][j] = {0.f, 0.f, 0.f, 0.f};

  for (;;) {
    const int rowBase = bi * 128;
    const int colBase = bj * 128;
    const bool isDiag = (bi == bj);

    const int tt2 = tt + GRIDB;
    const bool hasNext = (tt2 < NTRI);
    int bi2 = 0, bj2 = 0;
    const u8 *gA2 = Xn, *gB2 = Xn;
    if (hasNext) {
      bi2 = tri_decode_bi(tt2);
      bj2 = tt2 - bi2 * (bi2 + 1) / 2;
      gA2 = Xn + (size_t)(bi2 * 128 + srow) * DBYTES + goff;
      gB2 = Xn + (size_t)(bj2 * 128 + srow) * DBYTES + goff;
    }

#pragma unroll
    for (int c = 0; c < 4; ++c) {
      // issue next chunk (cur tile c+1, or next tile's chunk 0) -> buf (c+1)&1
      if (c < 3) {
        ISSUE(gA, gB, (c + 1) * 128, (c + 1) & 1);
        WAIT_VMCNT(8);  // chunk c landed; next chunk's 8 stay in flight
      } else if (hasNext) {
        ISSUE(gA2, gB2, 0, 0);
        WAIT_VMCNT(8);
      } else {
        WAIT_VMCNT(0);  // final chunk of final tile: full drain once
      }
      __builtin_amdgcn_s_barrier();
      asm volatile("" ::: "memory");
      __builtin_amdgcn_sched_barrier(0);

      COMPUTE(c & 1);

      if (c == 3) {
        // epilogue: e = exp((c-1)/T). C/D layout: col=lane&15, row=quad*4+reg.
        // Row-sum over l15 on the VALU pipe (DPP row_shr; sum in lane 15);
        // col-sums via 8 quad-axis shuffles/wave. Runs while next tile's
        // chunk-0 loads are in flight.
        if (isDiag) {
#pragma unroll
          for (int mi = 0; mi < 4; mi++) {
#pragma unroll
            for (int r = 0; r < 4; r++) {
              const int row = rowBase + wm * 64 + mi * 16 + quad * 4 + r;
              float rs = 0.0f;
#pragma unroll
              for (int ni = 0; ni < 4; ni++) {
                const int col = colBase + wn * 64 + ni * 16 + l15;
                const float e = __expf((acc[mi][ni][r] - 1.0f) * INV_T);
                rs += (row == col) ? 0.0f : e;
              }
              rs = dpp_shr_add<DPP_ROW_SHR1>(rs);
              rs = dpp_shr_add<DPP_ROW_SHR2>(rs);
              rs = dpp_shr_add<DPP_ROW_SHR4>(rs);
              rs = dpp_shr_add<DPP_ROW_SHR8>(rs);
              if (l15 == 15) atomicAdd(&tsum[row], rs);
            }
          }
        } else {
          float csum[4] = {0.f, 0.f, 0.f, 0.f};
#pragma unroll
          for (int mi = 0; mi < 4; mi++) {
#pragma unroll
            for (int r = 0; r < 4; r++) {
              const int row = rowBase + wm * 64 + mi * 16 + quad * 4 + r;
              float rs = 0.0f;
#pragma unroll
              for (int ni = 0; ni < 4; ni++) {
                const float e = __expf((acc[mi][ni][r] - 1.0f) * INV_T);
                rs += e;
                csum[ni] += e;
              }
              rs = dpp_shr_add<DPP_ROW_SHR1>(rs);
              rs = dpp_shr_add<DPP_ROW_SHR2>(rs);
              rs = dpp_shr_add<DPP_ROW_SHR4>(rs);
              rs = dpp_shr_add<DPP_ROW_SHR8>(rs);
              if (l15 == 15) atomicAdd(&tsum[row], rs);
            }
          }
#pragma unroll
          for (int ni = 0; ni < 4; ni++) {
            csum[ni] += __shfl_xor(csum[ni], 16);
            csum[ni] += __shfl_xor(csum[ni], 32);
            if (quad == 0)
              atomicAdd(&tsum[colBase + wn * 64 + ni * 16 + l15], csum[ni]);
          }
        }
        // reset accumulators for the next tile
#pragma unroll
        for (int i = 0; i < 4; i++)
#pragma unroll
          for (int j = 0; j < 4; j++) acc[i][j] = {0.f, 0.f, 0.f, 0.f};
      }
      asm volatile("" ::: "memory");
      __builtin_amdgcn_s_barrier();  // buf (c&1) free for overwrite next step
    }

    if (!hasNext) break;
    tt = tt2; bi = bi2; bj = bj2; gA = gA2; gB = gB2;
  }
#undef ISSUE
#undef COMPUTE
}

// ---- kernel 3: loss = mean_i log1p(t_i), 32 blocks + atomic accumulate -----
__global__ __launch_bounds__(256) void finalize_kernel(const float* __restrict__ tsum,
                                                       float* __restrict__ out) {
  const int i = blockIdx.x * 256 + threadIdx.x;
  float s = log1pf(tsum[i]);
#pragma unroll
  for (int m = 1; m < 64; m <<= 1) s += __shfl_xor(s, m);
  __shared__ float ws[4];
  if ((threadIdx.x & 63) == 0) ws[threadIdx.x >> 6] = s;
  __syncthreads();
  if (threadIdx.x == 0)
    atomicAdd(out, (ws[0] + ws[1] + ws[2] + ws[3]) * (1.0f / N_TOT));
}

// ---- launcher --------------------------------------------------------------
extern "C" void kernel_launch(void* const* d_in, const int* in_sizes, int n_in,
                              void* d_out, int out_size, void* d_ws, size_t ws_size,
                              hipStream_t stream) {
  const float* X = (const float*)d_in[0];
  float* out = (float*)d_out;

  float* tsum = (float*)d_ws;                       // 8192 fp32 = 32 KB
  u8* Xn = (u8*)d_ws + 65536;                       // 8192x512 fp8 = 4 MB

  normalize_kernel<<<N_TOT / 4, 256, 0, stream>>>(X, Xn, tsum, out);
  gemm_exp_rowsum<<<GRIDB, 256, 0, stream>>>(Xn, tsum);
  finalize_kernel<<<N_TOT / 256, 256, 0, stream>>>(tsum, out);
}